// Round 2
// baseline (767.140 us; speedup 1.0000x reference)
//
#include <hip/hip_runtime.h>
#include <math.h>

constexpr int N = 50000;
constexpr int E = 800000;
constexpr int D = 32;     // layer dim
constexpr int R = 20;     // relations
constexpr int B = 4;      // bases

// ---------------------------------------------------------------------------
// x0 = concat(feat[N,16], embed[idx][N,16])  -> x [N,32]
__global__ void build_x0(const float* __restrict__ feat,
                         const float* __restrict__ embed,
                         const int* __restrict__ idx,
                         float* __restrict__ x) {
    int t = blockIdx.x * blockDim.x + threadIdx.x;
    if (t >= N * D) return;
    int n = t >> 5, j = t & 31;
    float v;
    if (j < 16) v = feat[n * 16 + j];
    else        v = embed[idx[n] * 16 + (j - 16)];
    x[t] = v;
}

// ---------------------------------------------------------------------------
// Both layers' tiny precompute in one launch (2R blocks x 32 threads):
//   W[l][r]     = sum_b wcomp[l][r,b] * bases[l][b]      [R, D, D]
//   attnA[l][r] = attn_tab[r] @ Aw[l][64:96] + Ab[l]     [R, D]
__global__ void prep_layers(const float* __restrict__ bases0,
                            const float* __restrict__ wcomp0,
                            const float* __restrict__ Aw0,
                            const float* __restrict__ Ab0,
                            const float* __restrict__ bases1,
                            const float* __restrict__ wcomp1,
                            const float* __restrict__ Aw1,
                            const float* __restrict__ Ab1,
                            const float* __restrict__ attn_tab,
                            float* __restrict__ W,      // [2, R, D, D]
                            float* __restrict__ attnA)  // [2, R, D]
{
    int b = blockIdx.x;
    int l = b / R, r = b % R;
    int j = threadIdx.x;  // 0..31
    const float* bases = l ? bases1 : bases0;
    const float* wcomp = l ? wcomp1 : wcomp0;
    const float* Aw    = l ? Aw1 : Aw0;
    const float* Ab    = l ? Ab1 : Ab0;
    float w0 = wcomp[r * B + 0], w1 = wcomp[r * B + 1];
    float w2 = wcomp[r * B + 2], w3 = wcomp[r * B + 3];
    float* Wlr = W + ((size_t)l * R + r) * D * D;
    for (int i = 0; i < D; ++i) {
        int o = i * D + j;
        Wlr[o] = w0 * bases[0 * D * D + o] + w1 * bases[1 * D * D + o]
               + w2 * bases[2 * D * D + o] + w3 * bases[3 * D * D + o];
    }
    float acc = Ab[j];
    for (int k = 0; k < 32; ++k)
        acc = fmaf(attn_tab[r * 32 + k], Aw[(64 + k) * D + j], acc);
    attnA[((size_t)l * R + r) * D + j] = acc;
}

// ---------------------------------------------------------------------------
// Counting sort of edges by dst: histogram -> one-block scan -> scatter.
__global__ void zero_cnt(int* __restrict__ cnt) {
    int i = blockIdx.x * blockDim.x + threadIdx.x;
    if (i < N) cnt[i] = 0;
}

__global__ void hist_dst(const int* __restrict__ dst, int* __restrict__ cnt) {
    int e = blockIdx.x * blockDim.x + threadIdx.x;
    if (e < E) atomicAdd(&cnt[dst[e]], 1);
}

constexpr int SCAN_T = 1024;
__global__ __launch_bounds__(SCAN_T)
void scan_offsets(const int* __restrict__ cnt,
                  int* __restrict__ off,   // [N+1] exclusive offsets
                  int* __restrict__ cur) { // [N] scatter cursors
    __shared__ int ts[SCAN_T];
    int t = threadIdx.x;
    const int chunk = (N + SCAN_T - 1) / SCAN_T;  // 49
    int lo = t * chunk;
    int hi = lo + chunk; if (hi > N) hi = N; if (lo > N) lo = N;
    int sum = 0;
    for (int i = lo; i < hi; ++i) sum += cnt[i];
    ts[t] = sum;
    __syncthreads();
    for (int d = 1; d < SCAN_T; d <<= 1) {
        int v = (t >= d) ? ts[t - d] : 0;
        __syncthreads();
        ts[t] += v;
        __syncthreads();
    }
    int run = ts[t] - sum;  // exclusive prefix of this thread's chunk
    for (int i = lo; i < hi; ++i) {
        off[i] = run; cur[i] = run;
        run += cnt[i];
    }
    if (t == SCAN_T - 1) off[N] = ts[t];  // == E
}

__global__ void scatter_edges(const int* __restrict__ src,
                              const int* __restrict__ dst,
                              const int* __restrict__ ety,
                              int* __restrict__ cur,
                              int2* __restrict__ es) {  // [E] {src, etype}
    int e = blockIdx.x * blockDim.x + threadIdx.x;
    if (e >= E) return;
    int d = dst[e];
    int pos = atomicAdd(&cur[d], 1);
    es[pos] = make_int2(src[e], ety[e]);
}

// ---------------------------------------------------------------------------
// Node stage: sA[n] = x[n] @ Aw[0:32]  (gathered per-edge by src later)
__global__ void node_stage(const float* __restrict__ x,
                           const float* __restrict__ Aw,
                           float* __restrict__ sA) {
    int t = blockIdx.x * blockDim.x + threadIdx.x;
    int n = t >> 5, j = t & 31;
    if (n >= N) return;
    float xv = x[n * D + j];
    float sa = 0.f;
#pragma unroll
    for (int i = 0; i < D; ++i)
        sa = fmaf(__shfl(xv, i, 32), Aw[i * D + j], sa);
    sA[n * D + j] = sa;
}

// ---------------------------------------------------------------------------
// Segmented edge aggregation: 32 lanes per destination node.
// Per node: recompute dA[n], curr[n] (cheap, N-scaled), then walk the
// contiguous edge segment accumulating score*msg in registers; single write.
__global__ void edge_agg(const float* __restrict__ x,
                         const float* __restrict__ sA,
                         const float* __restrict__ attnA,
                         const float* __restrict__ W,
                         const float* __restrict__ Aw,
                         const float* __restrict__ selfw,
                         const float* __restrict__ Bw,
                         const float* __restrict__ Bb,
                         const int* __restrict__ off,
                         const int2* __restrict__ es,
                         float* __restrict__ out) {
    int t = blockIdx.x * blockDim.x + threadIdx.x;
    int n = t >> 5, j = t & 31;
    if (n >= N) return;

    float xn = x[n * D + j];
    float dAv = 0.f, cu = 0.f;
#pragma unroll
    for (int i = 0; i < D; ++i) {
        float xi = __shfl(xn, i, 32);
        dAv = fmaf(xi, Aw[(D + i) * D + j], dAv);
        cu  = fmaf(xi, selfw[i * D + j], cu);
    }

    float bw = Bw[j], bb = Bb[0];
    float acc = 0.f;
    int start = off[n], end = off[n + 1];
    for (int k = start; k < end; ++k) {
        int2 e = es[k];
        int s = e.x, r = e.y;
        float xv = x[s * D + j];
        const float* Wr = W + (size_t)r * D * D;
        float m = 0.f;
#pragma unroll
        for (int i = 0; i < D; ++i)
            m = fmaf(__shfl(xv, i, 32), Wr[i * D + j], m);
        float h = fmaxf(sA[s * D + j] + dAv + attnA[r * D + j], 0.f);
        float p = h * bw;
#pragma unroll
        for (int o = 16; o > 0; o >>= 1)
            p += __shfl_xor(p, o, 32);
        float sc = 1.f / (1.f + __expf(-(p + bb)));
        acc = fmaf(sc, m, acc);
    }
    out[n * D + j] = fmaxf(acc + cu, 0.f);
}

// ---------------------------------------------------------------------------
extern "C" void kernel_launch(void* const* d_in, const int* in_sizes, int n_in,
                              void* d_out, int out_size, void* d_ws, size_t ws_size,
                              hipStream_t stream) {
    const float* feat  = (const float*)d_in[0];
    const float* embed = (const float*)d_in[1];
    const float* attn  = (const float*)d_in[2];
    const int*   idx   = (const int*)d_in[3];
    const int*   src   = (const int*)d_in[4];
    const int*   dst   = (const int*)d_in[5];
    const int*   ety   = (const int*)d_in[6];
    const float* bases[2] = {(const float*)d_in[7],  (const float*)d_in[14]};
    const float* wcomp[2] = {(const float*)d_in[8],  (const float*)d_in[15]};
    const float* selfw[2] = {(const float*)d_in[9],  (const float*)d_in[16]};
    const float* Aw[2]    = {(const float*)d_in[10], (const float*)d_in[17]};
    const float* Ab[2]    = {(const float*)d_in[11], (const float*)d_in[18]};
    const float* Bw[2]    = {(const float*)d_in[12], (const float*)d_in[19]};
    const float* Bb[2]    = {(const float*)d_in[13], (const float*)d_in[20]};
    float* out = (float*)d_out;

    // --- workspace layout (element offsets in 4B units, 8B-aligned where needed)
    float* ws = (float*)d_ws;
    size_t o = 0;
    float* x0    = ws + o; o += (size_t)N * D;          // 1.6e6
    float* x1    = ws + o; o += (size_t)N * D;
    float* sA    = ws + o; o += (size_t)N * D;
    float* W     = ws + o; o += (size_t)2 * R * D * D;  // 40960
    float* attnA = ws + o; o += (size_t)2 * R * D;      // 1280
    o = (o + 1) & ~(size_t)1;                           // 8B align
    int2* es     = (int2*)(ws + o); o += (size_t)2 * E; // int2[E]
    int* cnt     = (int*)(ws + o);  o += N;
    int* off     = (int*)(ws + o);  o += N + 2;
    int* cur     = (int*)(ws + o);  o += N;
    // total ~6.6M elements ~26.4 MB

    dim3 blk(256);
    int gx = (N * D + 255) / 256;   // node-parallel, 32 lanes/node
    int ge = (E + 255) / 256;       // edge-parallel, 1 thread/edge
    int gn = (N + 255) / 256;

    // sort pipeline (graph is shared by both layers)
    zero_cnt<<<gn, blk, 0, stream>>>(cnt);
    build_x0<<<gx, blk, 0, stream>>>(feat, embed, idx, x0);
    prep_layers<<<2 * R, 32, 0, stream>>>(bases[0], wcomp[0], Aw[0], Ab[0],
                                          bases[1], wcomp[1], Aw[1], Ab[1],
                                          attn, W, attnA);
    hist_dst<<<ge, blk, 0, stream>>>(dst, cnt);
    scan_offsets<<<1, SCAN_T, 0, stream>>>(cnt, off, cur);
    scatter_edges<<<ge, blk, 0, stream>>>(src, dst, ety, cur, es);

    // layer 0: x0 -> x1
    node_stage<<<gx, blk, 0, stream>>>(x0, Aw[0], sA);
    edge_agg<<<gx, blk, 0, stream>>>(x0, sA, attnA, W, Aw[0], selfw[0],
                                     Bw[0], Bb[0], off, es, x1);
    // layer 1: x1 -> out
    node_stage<<<gx, blk, 0, stream>>>(x1, Aw[1], sA);
    edge_agg<<<gx, blk, 0, stream>>>(x1, sA, attnA + (size_t)R * D,
                                     W + (size_t)R * D * D, Aw[1], selfw[1],
                                     Bw[1], Bb[1], off, es, out);
}

// Round 3
// 577.972 us; speedup vs baseline: 1.3273x; 1.3273x over previous
//
#include <hip/hip_runtime.h>
#include <math.h>

constexpr int N = 50000;
constexpr int E = 800000;
constexpr int D = 32;     // layer dim
constexpr int R = 20;     // relations
constexpr int B = 4;      // bases
constexpr int EPB = 8;    // edges per block in edge kernel (256 thr / 32)

// ---------------------------------------------------------------------------
// x0 = concat(feat[N,16], embed[idx][N,16])  -> x [N,32]
__global__ void build_x0(const float* __restrict__ feat,
                         const float* __restrict__ embed,
                         const int* __restrict__ idx,
                         float* __restrict__ x) {
    int t = blockIdx.x * blockDim.x + threadIdx.x;
    if (t >= N * D) return;
    int n = t >> 5, j = t & 31;
    float v;
    if (j < 16) v = feat[n * 16 + j];
    else        v = embed[idx[n] * 16 + (j - 16)];
    x[t] = v;
}

// ---------------------------------------------------------------------------
// attnA[l][r] = attn_tab[r] @ Aw[l][64:96] + Ab[l]    [2, R, D]
__global__ void prep_attnA(const float* __restrict__ attn_tab,
                           const float* __restrict__ Aw0,
                           const float* __restrict__ Ab0,
                           const float* __restrict__ Aw1,
                           const float* __restrict__ Ab1,
                           float* __restrict__ attnA) {
    int b = blockIdx.x;           // 0..2R-1
    int l = b / R, r = b % R;
    int j = threadIdx.x;          // 0..31
    const float* Aw = l ? Aw1 : Aw0;
    const float* Ab = l ? Ab1 : Ab0;
    float acc = Ab[j];
    for (int k = 0; k < 32; ++k)
        acc = fmaf(attn_tab[r * 32 + k], Aw[(64 + k) * D + j], acc);
    attnA[((size_t)l * R + r) * D + j] = acc;
}

// ---------------------------------------------------------------------------
// Counting sort of edges by dst.
__global__ void zero_cnt(int* __restrict__ cnt) {
    int i = blockIdx.x * blockDim.x + threadIdx.x;
    if (i < N) cnt[i] = 0;
}

__global__ void hist_dst(const int* __restrict__ dst, int* __restrict__ cnt) {
    int e = blockIdx.x * blockDim.x + threadIdx.x;
    if (e < E) atomicAdd(&cnt[dst[e]], 1);
}

constexpr int SCAN_T = 1024;
__global__ __launch_bounds__(SCAN_T)
void scan_offsets(const int* __restrict__ cnt,
                  int* __restrict__ off,   // [N+1]
                  int* __restrict__ cur) { // [N]
    __shared__ int ts[SCAN_T];
    int t = threadIdx.x;
    const int chunk = (N + SCAN_T - 1) / SCAN_T;
    int lo = t * chunk;
    int hi = lo + chunk; if (hi > N) hi = N; if (lo > N) lo = N;
    int sum = 0;
    for (int i = lo; i < hi; ++i) sum += cnt[i];
    ts[t] = sum;
    __syncthreads();
    for (int d = 1; d < SCAN_T; d <<= 1) {
        int v = (t >= d) ? ts[t - d] : 0;
        __syncthreads();
        ts[t] += v;
        __syncthreads();
    }
    int run = ts[t] - sum;
    for (int i = lo; i < hi; ++i) {
        off[i] = run; cur[i] = run;
        run += cnt[i];
    }
    if (t == SCAN_T - 1) off[N] = ts[t];
}

// es4[k] = {src, etype, dst, 0} in dst-sorted order
__global__ void scatter_edges(const int* __restrict__ src,
                              const int* __restrict__ dst,
                              const int* __restrict__ ety,
                              int* __restrict__ cur,
                              int4* __restrict__ es4) {
    int e = blockIdx.x * blockDim.x + threadIdx.x;
    if (e >= E) return;
    int d = dst[e];
    int pos = atomicAdd(&cur[d], 1);
    es4[pos] = make_int4(src[e], ety[e], d, 0);
}

// ---------------------------------------------------------------------------
// Node stage (per layer), 32 lanes per node:
//   sA[n] = x[n]@Aw[0:32],  dA[n] = x[n]@Aw[32:64]
//   xb[n,b,:] = x[n]@bases[b]  (b=0..3)   -> per-edge msg becomes 4 fma
//   nei[n] = 0
__global__ void node_stage(const float* __restrict__ x,
                           const float* __restrict__ Aw,
                           const float* __restrict__ bases,
                           float* __restrict__ sA,
                           float* __restrict__ dA,
                           float* __restrict__ xb,
                           float* __restrict__ nei) {
    int t = blockIdx.x * blockDim.x + threadIdx.x;
    int n = t >> 5, j = t & 31;
    if (n >= N) return;
    float xv = x[n * D + j];
    float sa = 0.f, da = 0.f, b0 = 0.f, b1 = 0.f, b2 = 0.f, b3 = 0.f;
#pragma unroll
    for (int i = 0; i < D; ++i) {
        float xi = __shfl(xv, i, 32);
        sa = fmaf(xi, Aw[i * D + j], sa);
        da = fmaf(xi, Aw[(D + i) * D + j], da);
        b0 = fmaf(xi, bases[0 * D * D + i * D + j], b0);
        b1 = fmaf(xi, bases[1 * D * D + i * D + j], b1);
        b2 = fmaf(xi, bases[2 * D * D + i * D + j], b2);
        b3 = fmaf(xi, bases[3 * D * D + i * D + j], b3);
    }
    sA[n * D + j] = sa;
    dA[n * D + j] = da;
    float* xbn = xb + (size_t)n * 4 * D;
    xbn[0 * D + j] = b0;
    xbn[1 * D + j] = b1;
    xbn[2 * D + j] = b2;
    xbn[3 * D + j] = b3;
    nei[n * D + j] = 0.f;
}

// ---------------------------------------------------------------------------
// Edge stage over dst-sorted edges: 8 edges/block, 32 lanes/edge.
//   msg_j = sum_b wcomp[r,b] * xb[s,b,j]            (4 fma)
//   a     = sigmoid(dot(relu(sA[s]+dA[d]+attnA[r]), Bw) + Bb)
//   LDS segmented reduction over equal-dst runs -> 1 atomic per run.
__global__ __launch_bounds__(256)
void edge_stage(const float* __restrict__ sA,
                const float* __restrict__ dA,
                const float* __restrict__ xb,
                const float* __restrict__ attnA,
                const float* __restrict__ wcomp,
                const float* __restrict__ Bw,
                const float* __restrict__ Bb,
                const int4* __restrict__ es4,
                float* __restrict__ nei) {
    __shared__ float accs[EPB][32];
    __shared__ int ed[EPB];
    int t = blockIdx.x * blockDim.x + threadIdx.x;
    int k = t >> 5;                 // sorted edge index
    int j = t & 31;
    int g = threadIdx.x >> 5;       // group within block
    bool valid = (k < E);

    int d = -1 - g;                 // unique invalid marker per group
    float val = 0.f;
    if (valid) {
        int4 e = es4[k];
        int s = e.x, r = e.y;
        d = e.z;
        // attention score
        float h = sA[s * D + j] + dA[d * D + j] + attnA[r * D + j];
        h = fmaxf(h, 0.f);
        float p = h * Bw[j];
#pragma unroll
        for (int o = 16; o > 0; o >>= 1)
            p += __shfl_xor(p, o, 32);
        float a = 1.f / (1.f + __expf(-(p + Bb[0])));
        // message: 4 fma via basis factorization
        const float4 wc = *(const float4*)(wcomp + r * B);
        const float* xbs = xb + (size_t)s * 4 * D;
        float m = wc.x * xbs[0 * D + j];
        m = fmaf(wc.y, xbs[1 * D + j], m);
        m = fmaf(wc.z, xbs[2 * D + j], m);
        m = fmaf(wc.w, xbs[3 * D + j], m);
        val = a * m;
    }
    accs[g][j] = val;
    if (j == 0) ed[g] = d;
    __syncthreads();

    // run leaders flush their run with one atomic per column
    bool lead = (g == 0) || (ed[g - 1] != d);
    if (lead && d >= 0) {
        float sum = accs[g][j];
        for (int g2 = g + 1; g2 < EPB; ++g2) {
            if (ed[g2] != d) break;
            sum += accs[g2][j];
        }
        atomicAdd(&nei[(size_t)d * D + j], sum);
    }
}

// ---------------------------------------------------------------------------
// out[n] = relu(nei[n] + x[n]@selfw)   (32 lanes/node; safe in-place per row)
__global__ void finalize(const float* __restrict__ nei,
                         const float* __restrict__ x,
                         const float* __restrict__ selfw,
                         float* __restrict__ out) {
    int t = blockIdx.x * blockDim.x + threadIdx.x;
    int n = t >> 5, j = t & 31;
    if (n >= N) return;
    float xv = x[n * D + j];
    float cu = 0.f;
#pragma unroll
    for (int i = 0; i < D; ++i)
        cu = fmaf(__shfl(xv, i, 32), selfw[i * D + j], cu);
    out[n * D + j] = fmaxf(nei[n * D + j] + cu, 0.f);
}

// ---------------------------------------------------------------------------
extern "C" void kernel_launch(void* const* d_in, const int* in_sizes, int n_in,
                              void* d_out, int out_size, void* d_ws, size_t ws_size,
                              hipStream_t stream) {
    const float* feat  = (const float*)d_in[0];
    const float* embed = (const float*)d_in[1];
    const float* attn  = (const float*)d_in[2];
    const int*   idx   = (const int*)d_in[3];
    const int*   src   = (const int*)d_in[4];
    const int*   dst   = (const int*)d_in[5];
    const int*   ety   = (const int*)d_in[6];
    const float* bases[2] = {(const float*)d_in[7],  (const float*)d_in[14]};
    const float* wcomp[2] = {(const float*)d_in[8],  (const float*)d_in[15]};
    const float* selfw[2] = {(const float*)d_in[9],  (const float*)d_in[16]};
    const float* Aw[2]    = {(const float*)d_in[10], (const float*)d_in[17]};
    const float* Ab[2]    = {(const float*)d_in[11], (const float*)d_in[18]};
    const float* Bw[2]    = {(const float*)d_in[12], (const float*)d_in[19]};
    const float* Bb[2]    = {(const float*)d_in[13], (const float*)d_in[20]};
    float* out = (float*)d_out;

    // --- workspace layout (float elements; es4 kept 16B-aligned) ---
    float* ws = (float*)d_ws;
    size_t o = 0;
    float* x0    = ws + o; o += (size_t)N * D;            // 1.6M
    float* sA    = ws + o; o += (size_t)N * D;            // 1.6M
    float* dA    = ws + o; o += (size_t)N * D;            // 1.6M
    float* nei   = ws + o; o += (size_t)N * D;            // 1.6M
    float* xb    = ws + o; o += (size_t)N * B * D;        // 6.4M
    float* attnA = ws + o; o += (size_t)2 * R * D;        // 1280
    o = (o + 3) & ~(size_t)3;                             // 16B align
    int4* es4    = (int4*)(ws + o); o += (size_t)4 * E;   // 3.2M
    int* cnt     = (int*)(ws + o);  o += N;
    int* off     = (int*)(ws + o);  o += N + 2;
    int* cur     = (int*)(ws + o);  o += N;
    // ~16.3M floats ~= 65 MB

    dim3 blk(256);
    int gx = (N * D + 255) / 256;     // 6250: 32 lanes/node
    int ge = (E + 255) / 256;         // 3125: 1 thread/edge
    int gn = (N + 255) / 256;         // 196
    int gE = (E + EPB - 1) / EPB;     // 100000: 8 edges/block

    // one-time graph sort + feature build
    zero_cnt<<<gn, blk, 0, stream>>>(cnt);
    build_x0<<<gx, blk, 0, stream>>>(feat, embed, idx, x0);
    prep_attnA<<<2 * R, 32, 0, stream>>>(attn, Aw[0], Ab[0], Aw[1], Ab[1], attnA);
    hist_dst<<<ge, blk, 0, stream>>>(dst, cnt);
    scan_offsets<<<1, SCAN_T, 0, stream>>>(cnt, off, cur);
    scatter_edges<<<ge, blk, 0, stream>>>(src, dst, ety, cur, es4);

    // layer 0: x0 -> d_out (used as x1)
    node_stage<<<gx, blk, 0, stream>>>(x0, Aw[0], bases[0], sA, dA, xb, nei);
    edge_stage<<<gE, blk, 0, stream>>>(sA, dA, xb, attnA, wcomp[0], Bw[0], Bb[0],
                                       es4, nei);
    finalize<<<gx, blk, 0, stream>>>(nei, x0, selfw[0], out);

    // layer 1: d_out -> d_out (in-place safe: per-row read-then-write)
    node_stage<<<gx, blk, 0, stream>>>(out, Aw[1], bases[1], sA, dA, xb, nei);
    edge_stage<<<gE, blk, 0, stream>>>(sA, dA, xb, attnA + (size_t)R * D,
                                       wcomp[1], Bw[1], Bb[1], es4, nei);
    finalize<<<gx, blk, 0, stream>>>(nei, out, selfw[1], out);
}

// Round 4
// 480.579 us; speedup vs baseline: 1.5963x; 1.2027x over previous
//
#include <hip/hip_runtime.h>
#include <math.h>

constexpr int N = 50000;
constexpr int E = 800000;
constexpr int D = 32;     // layer dim
constexpr int R = 20;     // relations
constexpr int B = 4;      // bases
constexpr int EPB = 8;    // edges per block in edge kernel (256 thr / 32)

// ---------------------------------------------------------------------------
// x0 = concat(feat[N,16], embed[idx][N,16])  -> x [N,32]
__global__ void build_x0(const float* __restrict__ feat,
                         const float* __restrict__ embed,
                         const int* __restrict__ idx,
                         float* __restrict__ x) {
    int t = blockIdx.x * blockDim.x + threadIdx.x;
    if (t >= N * D) return;
    int n = t >> 5, j = t & 31;
    float v;
    if (j < 16) v = feat[n * 16 + j];
    else        v = embed[idx[n] * 16 + (j - 16)];
    x[t] = v;
}

// ---------------------------------------------------------------------------
// attnA[l][r] = attn_tab[r] @ Aw[l][64:96] + Ab[l]    [2, R, D]
__global__ void prep_attnA(const float* __restrict__ attn_tab,
                           const float* __restrict__ Aw0,
                           const float* __restrict__ Ab0,
                           const float* __restrict__ Aw1,
                           const float* __restrict__ Ab1,
                           float* __restrict__ attnA) {
    int b = blockIdx.x;           // 0..2R-1
    int l = b / R, r = b % R;
    int j = threadIdx.x;          // 0..31
    const float* Aw = l ? Aw1 : Aw0;
    const float* Ab = l ? Ab1 : Ab0;
    float acc = Ab[j];
    for (int k = 0; k < 32; ++k)
        acc = fmaf(attn_tab[r * 32 + k], Aw[(64 + k) * D + j], acc);
    attnA[((size_t)l * R + r) * D + j] = acc;
}

// ---------------------------------------------------------------------------
// Counting sort of edges by dst.
__global__ void zero_cnt(int* __restrict__ cnt) {
    int i = blockIdx.x * blockDim.x + threadIdx.x;
    if (i < N) cnt[i] = 0;
}

__global__ void hist_dst(const int* __restrict__ dst, int* __restrict__ cnt) {
    int e = blockIdx.x * blockDim.x + threadIdx.x;
    if (e < E) atomicAdd(&cnt[dst[e]], 1);
}

// --- hierarchical exclusive scan of cnt[N] -> off[N+1], cur[N] -------------
constexpr int SCB = 1024;
constexpr int NSCB = (N + SCB - 1) / SCB;   // 49

__global__ __launch_bounds__(SCB)
void scan_block_sums(const int* __restrict__ cnt, int* __restrict__ bsum) {
    __shared__ int sdata[SCB];
    int i = blockIdx.x * SCB + threadIdx.x;
    sdata[threadIdx.x] = (i < N) ? cnt[i] : 0;
    __syncthreads();
    for (int s = SCB / 2; s > 0; s >>= 1) {
        if (threadIdx.x < s) sdata[threadIdx.x] += sdata[threadIdx.x + s];
        __syncthreads();
    }
    if (threadIdx.x == 0) bsum[blockIdx.x] = sdata[0];
}

__global__ void scan_bsum(int* __restrict__ bsum) {
    int t = threadIdx.x;  // 64 threads, one wave
    int orig = (t < NSCB) ? bsum[t] : 0;
    int v = orig;
#pragma unroll
    for (int d = 1; d < 64; d <<= 1) {
        int u = __shfl_up(v, d, 64);
        if (t >= d) v += u;
    }
    if (t < NSCB) bsum[t] = v - orig;  // exclusive prefix of block sums
}

__global__ __launch_bounds__(SCB)
void scan_final(const int* __restrict__ cnt, const int* __restrict__ bsum,
                int* __restrict__ off, int* __restrict__ cur) {
    __shared__ int sdata[SCB];
    int i = blockIdx.x * SCB + threadIdx.x;
    int v = (i < N) ? cnt[i] : 0;
    sdata[threadIdx.x] = v;
    __syncthreads();
    for (int d = 1; d < SCB; d <<= 1) {
        int u = (threadIdx.x >= (unsigned)d) ? sdata[threadIdx.x - d] : 0;
        __syncthreads();
        sdata[threadIdx.x] += u;
        __syncthreads();
    }
    if (i < N) {
        int excl = sdata[threadIdx.x] - v + bsum[blockIdx.x];
        off[i] = excl;
        cur[i] = excl;
        if (i == N - 1) off[N] = excl + v;   // == E
    }
}

// es4[k] = {src, etype, dst, 0} in dst-sorted order
__global__ void scatter_edges(const int* __restrict__ src,
                              const int* __restrict__ dst,
                              const int* __restrict__ ety,
                              int* __restrict__ cur,
                              int4* __restrict__ es4) {
    int e = blockIdx.x * blockDim.x + threadIdx.x;
    if (e >= E) return;
    int d = dst[e];
    int pos = atomicAdd(&cur[d], 1);
    es4[pos] = make_int4(src[e], ety[e], d, 0);
}

// ---------------------------------------------------------------------------
// Node stage (per layer), 32 lanes per node:
//   sA[n] = x[n]@Aw[0:32],  dA[n] = x[n]@Aw[32:64]
//   xb[n,b,:] = x[n]@bases[b]  (b=0..3)   -> per-edge msg becomes 4 fma
//   nei[n] = 0
__global__ void node_stage(const float* __restrict__ x,
                           const float* __restrict__ Aw,
                           const float* __restrict__ bases,
                           float* __restrict__ sA,
                           float* __restrict__ dA,
                           float* __restrict__ xb,
                           float* __restrict__ nei) {
    int t = blockIdx.x * blockDim.x + threadIdx.x;
    int n = t >> 5, j = t & 31;
    if (n >= N) return;
    float xv = x[n * D + j];
    float sa = 0.f, da = 0.f, b0 = 0.f, b1 = 0.f, b2 = 0.f, b3 = 0.f;
#pragma unroll
    for (int i = 0; i < D; ++i) {
        float xi = __shfl(xv, i, 32);
        sa = fmaf(xi, Aw[i * D + j], sa);
        da = fmaf(xi, Aw[(D + i) * D + j], da);
        b0 = fmaf(xi, bases[0 * D * D + i * D + j], b0);
        b1 = fmaf(xi, bases[1 * D * D + i * D + j], b1);
        b2 = fmaf(xi, bases[2 * D * D + i * D + j], b2);
        b3 = fmaf(xi, bases[3 * D * D + i * D + j], b3);
    }
    sA[n * D + j] = sa;
    dA[n * D + j] = da;
    float* xbn = xb + (size_t)n * 4 * D;
    xbn[0 * D + j] = b0;
    xbn[1 * D + j] = b1;
    xbn[2 * D + j] = b2;
    xbn[3 * D + j] = b3;
    nei[n * D + j] = 0.f;
}

// ---------------------------------------------------------------------------
// Edge stage over dst-sorted edges: 8 edges/block, 32 lanes/edge.
//   msg_j = sum_b wcomp[r,b] * xb[s,b,j]            (4 fma)
//   a     = sigmoid(dot(relu(sA[s]+dA[d]+attnA[r]), Bw) + Bb)
//   LDS segmented reduction over equal-dst runs -> 1 atomic per run.
__global__ __launch_bounds__(256)
void edge_stage(const float* __restrict__ sA,
                const float* __restrict__ dA,
                const float* __restrict__ xb,
                const float* __restrict__ attnA,
                const float* __restrict__ wcomp,
                const float* __restrict__ Bw,
                const float* __restrict__ Bb,
                const int4* __restrict__ es4,
                float* __restrict__ nei) {
    __shared__ float accs[EPB][32];
    __shared__ int ed[EPB];
    int t = blockIdx.x * blockDim.x + threadIdx.x;
    int k = t >> 5;                 // sorted edge index
    int j = t & 31;
    int g = threadIdx.x >> 5;       // group within block
    bool valid = (k < E);

    int d = -1 - g;                 // unique invalid marker per group
    float val = 0.f;
    if (valid) {
        int4 e = es4[k];
        int s = e.x, r = e.y;
        d = e.z;
        // attention score
        float h = sA[s * D + j] + dA[d * D + j] + attnA[r * D + j];
        h = fmaxf(h, 0.f);
        float p = h * Bw[j];
#pragma unroll
        for (int o = 16; o > 0; o >>= 1)
            p += __shfl_xor(p, o, 32);
        float a = 1.f / (1.f + __expf(-(p + Bb[0])));
        // message: 4 fma via basis factorization
        const float4 wc = *(const float4*)(wcomp + r * B);
        const float* xbs = xb + (size_t)s * 4 * D;
        float m = wc.x * xbs[0 * D + j];
        m = fmaf(wc.y, xbs[1 * D + j], m);
        m = fmaf(wc.z, xbs[2 * D + j], m);
        m = fmaf(wc.w, xbs[3 * D + j], m);
        val = a * m;
    }
    accs[g][j] = val;
    if (j == 0) ed[g] = d;
    __syncthreads();

    // run leaders flush their run with one atomic per column
    bool lead = (g == 0) || (ed[g - 1] != d);
    if (lead && d >= 0) {
        float sum = accs[g][j];
        for (int g2 = g + 1; g2 < EPB; ++g2) {
            if (ed[g2] != d) break;
            sum += accs[g2][j];
        }
        atomicAdd(&nei[(size_t)d * D + j], sum);
    }
}

// ---------------------------------------------------------------------------
// out[n] = relu(nei[n] + x[n]@selfw)   (32 lanes/node; safe in-place per row)
__global__ void finalize(const float* __restrict__ nei,
                         const float* __restrict__ x,
                         const float* __restrict__ selfw,
                         float* __restrict__ out) {
    int t = blockIdx.x * blockDim.x + threadIdx.x;
    int n = t >> 5, j = t & 31;
    if (n >= N) return;
    float xv = x[n * D + j];
    float cu = 0.f;
#pragma unroll
    for (int i = 0; i < D; ++i)
        cu = fmaf(__shfl(xv, i, 32), selfw[i * D + j], cu);
    out[n * D + j] = fmaxf(nei[n * D + j] + cu, 0.f);
}

// ---------------------------------------------------------------------------
extern "C" void kernel_launch(void* const* d_in, const int* in_sizes, int n_in,
                              void* d_out, int out_size, void* d_ws, size_t ws_size,
                              hipStream_t stream) {
    const float* feat  = (const float*)d_in[0];
    const float* embed = (const float*)d_in[1];
    const float* attn  = (const float*)d_in[2];
    const int*   idx   = (const int*)d_in[3];
    const int*   src   = (const int*)d_in[4];
    const int*   dst   = (const int*)d_in[5];
    const int*   ety   = (const int*)d_in[6];
    const float* bases[2] = {(const float*)d_in[7],  (const float*)d_in[14]};
    const float* wcomp[2] = {(const float*)d_in[8],  (const float*)d_in[15]};
    const float* selfw[2] = {(const float*)d_in[9],  (const float*)d_in[16]};
    const float* Aw[2]    = {(const float*)d_in[10], (const float*)d_in[17]};
    const float* Ab[2]    = {(const float*)d_in[11], (const float*)d_in[18]};
    const float* Bw[2]    = {(const float*)d_in[12], (const float*)d_in[19]};
    const float* Bb[2]    = {(const float*)d_in[13], (const float*)d_in[20]};
    float* out = (float*)d_out;

    // --- workspace layout (float elements; es4 kept 16B-aligned) ---
    float* ws = (float*)d_ws;
    size_t o = 0;
    float* x0    = ws + o; o += (size_t)N * D;            // 1.6M
    float* sA    = ws + o; o += (size_t)N * D;            // 1.6M
    float* dA    = ws + o; o += (size_t)N * D;            // 1.6M
    float* nei   = ws + o; o += (size_t)N * D;            // 1.6M
    float* xb    = ws + o; o += (size_t)N * B * D;        // 6.4M
    float* attnA = ws + o; o += (size_t)2 * R * D;        // 1280
    o = (o + 3) & ~(size_t)3;                             // 16B align
    int4* es4    = (int4*)(ws + o); o += (size_t)4 * E;   // 3.2M
    int* cnt     = (int*)(ws + o);  o += N;
    int* off     = (int*)(ws + o);  o += N + 2;
    int* cur     = (int*)(ws + o);  o += N;
    int* bsum    = (int*)(ws + o);  o += NSCB + 1;
    // ~16.3M floats ~= 65 MB

    dim3 blk(256);
    int gx = (N * D + 255) / 256;     // 6250: 32 lanes/node
    int ge = (E + 255) / 256;         // 3125: 1 thread/edge
    int gn = (N + 255) / 256;         // 196
    int gE = (E + EPB - 1) / EPB;     // 100000: 8 edges/block

    // one-time graph sort + feature build
    zero_cnt<<<gn, blk, 0, stream>>>(cnt);
    build_x0<<<gx, blk, 0, stream>>>(feat, embed, idx, x0);
    prep_attnA<<<2 * R, 32, 0, stream>>>(attn, Aw[0], Ab[0], Aw[1], Ab[1], attnA);
    hist_dst<<<ge, blk, 0, stream>>>(dst, cnt);
    scan_block_sums<<<NSCB, SCB, 0, stream>>>(cnt, bsum);
    scan_bsum<<<1, 64, 0, stream>>>(bsum);
    scan_final<<<NSCB, SCB, 0, stream>>>(cnt, bsum, off, cur);
    scatter_edges<<<ge, blk, 0, stream>>>(src, dst, ety, cur, es4);

    // layer 0: x0 -> d_out (used as x1)
    node_stage<<<gx, blk, 0, stream>>>(x0, Aw[0], bases[0], sA, dA, xb, nei);
    edge_stage<<<gE, blk, 0, stream>>>(sA, dA, xb, attnA, wcomp[0], Bw[0], Bb[0],
                                       es4, nei);
    finalize<<<gx, blk, 0, stream>>>(nei, x0, selfw[0], out);

    // layer 1: d_out -> d_out (in-place safe: per-row read-then-write)
    node_stage<<<gx, blk, 0, stream>>>(out, Aw[1], bases[1], sA, dA, xb, nei);
    edge_stage<<<gE, blk, 0, stream>>>(sA, dA, xb, attnA + (size_t)R * D,
                                       wcomp[1], Bw[1], Bb[1], es4, nei);
    finalize<<<gx, blk, 0, stream>>>(nei, out, selfw[1], out);
}